// Round 12
// baseline (86.769 us; speedup 1.0000x reference)
//
#include <hip/hip_runtime.h>

// Problem constants
#define B_    16
#define N1_   32
#define NL_   256
#define DM_   16
#define DOUT_ 16

#define NBN   (B_ * N1_)                  // 512 blocks
#define PROJ_ELEMS (NBN * NL_ * DOUT_)    // 2097152

// Flat LDS layout (float offsets), total 17408 floats = 69.6 KB -> 2 blocks/CU.
//   [0,1024)      weights Wq|Wk|Wv|Wo
//   [1024,5120)   QP (swizzled [256][16]) -- dead after Qp->regs; aliased by AT
//   [5120,9216)   ATX (AT rows 128..255; AT = [1024,9216) contiguous)
//   [9216,13312)  KP [256][16]
//   [13312,17408) VP [256][16]
// Epilogue aliases: EMBA [256][17] over QP/AT region, EMBB [256][17] from
// KP_OFF (spills 256 floats into dead VP region -- both dead by then).
#define WQ_OFF   0
#define WK_OFF   256
#define WV_OFF   512
#define WO_OFF   768
#define QP_OFF   1024
#define KP_OFF   9216
#define VP_OFF   13312
#define LDS_FLOATS 17408
#define EMBA_OFF QP_OFF
#define EMBB_OFF KP_OFF

// QP swizzle: row-major [256][16], bank-spread via (c+row)&15  (2-way, free)
#define QPA(row, c)  (QP_OFF + (row)*16 + (((c) + (row)) & 15))
// AT swizzle: [256][32] over the QP+ATX region, conflict-free via col^(row&31)
#define ATA(row, col) (QP_OFF + (row)*32 + ((col) ^ ((row) & 31)))

// Launch-bounds lore (measured): (512,2)->128 VGPR ok (r9/r11); (512,4)->64
// VGPR + catastrophic spill (r10); (256,2)->128-pinned, spills when live>128
// (r6-8). Here we need ~190 live: (256,1) lifts the cap to 512; ~200 VGPR
// still allows 2 waves/SIMD, and LDS 69.6 KB keeps 2 blocks/CU.
__global__ __launch_bounds__(256, 1)
void mha_relu_kernel(const float* __restrict__ Q,
                     const float* __restrict__ K,
                     const float* __restrict__ V,
                     const float* __restrict__ Wq,
                     const float* __restrict__ Wk,
                     const float* __restrict__ Wv,
                     const float* __restrict__ Wo,
                     float* __restrict__ proj_out,
                     float* __restrict__ attn_out)
{
    __shared__ float lds[LDS_FLOATS];

    const int tid = threadIdx.x;          // 0..255
    const int bn  = blockIdx.x;
    const int w   = tid >> 6;             // wave 0..3 = col slot
    const int l   = tid & 63;             // lane; owns rows 64j+l, j=0..3

    // ---- weights -> LDS ----
    lds[WQ_OFF + tid] = Wq[tid];
    lds[WK_OFF + tid] = Wk[tid];
    lds[WV_OFF + tid] = Wv[tid];
    lds[WO_OFF + tid] = Wo[tid];
    __syncthreads();

    const size_t inoff = (size_t)bn * NL_ * DM_;

    // ---- phase 1: per-row projections (thread t computes row t) ----
    {
        float rowbuf[16], acc[16];
        // Q row -> QP (swizzled)
        {
            const float4* p = (const float4*)(Q + inoff + (size_t)tid * DM_);
            #pragma unroll
            for (int i = 0; i < 4; ++i) {
                float4 t4 = p[i];
                rowbuf[4*i+0] = t4.x; rowbuf[4*i+1] = t4.y;
                rowbuf[4*i+2] = t4.z; rowbuf[4*i+3] = t4.w;
            }
            #pragma unroll
            for (int c = 0; c < 16; ++c) acc[c] = 0.f;
            #pragma unroll
            for (int i = 0; i < 16; ++i) {
                const float qi = rowbuf[i];
                #pragma unroll
                for (int c = 0; c < 16; ++c) acc[c] += qi * lds[WQ_OFF + i*16 + c];
            }
            #pragma unroll
            for (int c = 0; c < 16; ++c) lds[QPA(tid, c)] = acc[c];
        }
        // K row -> KP
        {
            const float4* p = (const float4*)(K + inoff + (size_t)tid * DM_);
            #pragma unroll
            for (int i = 0; i < 4; ++i) {
                float4 t4 = p[i];
                rowbuf[4*i+0] = t4.x; rowbuf[4*i+1] = t4.y;
                rowbuf[4*i+2] = t4.z; rowbuf[4*i+3] = t4.w;
            }
            #pragma unroll
            for (int c = 0; c < 16; ++c) acc[c] = 0.f;
            #pragma unroll
            for (int i = 0; i < 16; ++i) {
                const float ki = rowbuf[i];
                #pragma unroll
                for (int c = 0; c < 16; ++c) acc[c] += ki * lds[WK_OFF + i*16 + c];
            }
            #pragma unroll
            for (int c = 0; c < 16; ++c) lds[KP_OFF + tid*16 + c] = acc[c];
        }
        // V row -> VP
        {
            const float4* p = (const float4*)(V + inoff + (size_t)tid * DM_);
            #pragma unroll
            for (int i = 0; i < 4; ++i) {
                float4 t4 = p[i];
                rowbuf[4*i+0] = t4.x; rowbuf[4*i+1] = t4.y;
                rowbuf[4*i+2] = t4.z; rowbuf[4*i+3] = t4.w;
            }
            #pragma unroll
            for (int c = 0; c < 16; ++c) acc[c] = 0.f;
            #pragma unroll
            for (int i = 0; i < 16; ++i) {
                const float vi = rowbuf[i];
                #pragma unroll
                for (int c = 0; c < 16; ++c) acc[c] += vi * lds[WV_OFF + i*16 + c];
            }
            #pragma unroll
            for (int c = 0; c < 16; ++c) lds[VP_OFF + tid*16 + c] = acc[c];
        }
    }
    __syncthreads();

    // ---- this lane's 4 Qp rows -> registers (swizzled reads: 2-way, free) ----
    float Qp[4][16];
    #pragma unroll
    for (int j = 0; j < 4; ++j) {
        const int row = 64*j + l;
        #pragma unroll
        for (int c = 0; c < 16; ++c) Qp[j][c] = lds[QPA(row, c)];
    }

    float emb[4][16];
    #pragma unroll
    for (int j = 0; j < 4; ++j)
        #pragma unroll
        for (int c = 0; c < 16; ++c) emb[j][c] = 0.f;

    float* aout = attn_out + (size_t)bn * NL_ * NL_;

    // ---- main loop: 8 col-tiles of 32; wave w owns cols 8w..8w+8 of each;
    //      each broadcast KP/VP row (128 B) feeds 4 rows x 32 FMAs ----
    #pragma unroll 1
    for (int t = 0; t < 8; ++t) {
        float atr[4][8];
        #pragma unroll
        for (int e = 0; e < 8; ++e) {
            const int z = 32*t + 8*w + e;
            const float4 k0 = *(const float4*)&lds[KP_OFF + z*16 + 0];
            const float4 k1 = *(const float4*)&lds[KP_OFF + z*16 + 4];
            const float4 k2 = *(const float4*)&lds[KP_OFF + z*16 + 8];
            const float4 k3 = *(const float4*)&lds[KP_OFF + z*16 + 12];
            const float4 v0 = *(const float4*)&lds[VP_OFF + z*16 + 0];
            const float4 v1 = *(const float4*)&lds[VP_OFF + z*16 + 4];
            const float4 v2 = *(const float4*)&lds[VP_OFF + z*16 + 8];
            const float4 v3 = *(const float4*)&lds[VP_OFF + z*16 + 12];
            #pragma unroll
            for (int j = 0; j < 4; ++j) {
                float s0 = Qp[j][0]*k0.x + Qp[j][1]*k0.y + Qp[j][2]*k0.z + Qp[j][3]*k0.w
                         + Qp[j][4]*k1.x + Qp[j][5]*k1.y + Qp[j][6]*k1.z + Qp[j][7]*k1.w;
                float s1 = Qp[j][8]*k2.x + Qp[j][9]*k2.y + Qp[j][10]*k2.z + Qp[j][11]*k2.w
                         + Qp[j][12]*k3.x + Qp[j][13]*k3.y + Qp[j][14]*k3.z + Qp[j][15]*k3.w;
                s0 = fmaxf(s0, 0.f);
                s1 = fmaxf(s1, 0.f);
                atr[j][e] = 0.5f * (s0 + s1);
                emb[j][0]  += s0*v0.x; emb[j][1]  += s0*v0.y; emb[j][2]  += s0*v0.z; emb[j][3]  += s0*v0.w;
                emb[j][4]  += s0*v1.x; emb[j][5]  += s0*v1.y; emb[j][6]  += s0*v1.z; emb[j][7]  += s0*v1.w;
                emb[j][8]  += s1*v2.x; emb[j][9]  += s1*v2.y; emb[j][10] += s1*v2.z; emb[j][11] += s1*v2.w;
                emb[j][12] += s1*v3.x; emb[j][13] += s1*v3.y; emb[j][14] += s1*v3.z; emb[j][15] += s1*v3.w;
            }
        }
        __syncthreads();                  // prev tile's AT reads (and Qp loads) done
        #pragma unroll
        for (int j = 0; j < 4; ++j)
            #pragma unroll
            for (int e = 0; e < 8; ++e)
                lds[ATA(64*j + l, 8*w + e)] = atr[j][e];
        __syncthreads();
        // cooperative store: per wave-instr 2 rows x 32 cols = full 128-B lines
        #pragma unroll
        for (int i = 0; i < 32; ++i) {
            const int idx = i*256 + tid;  // over [256 rows][32 cols]
            const int row = idx >> 5;
            const int col = idx & 31;
            aout[(size_t)row * NL_ + 32*t + col] = lds[ATA(row, col)];
        }
    }

    // ---- emb reduction: 4 col-slot partials via 2 buffers, 2 barriers ----
    __syncthreads();                      // QP/AT/KP/VP all dead from here
    if (w == 0) {
        #pragma unroll
        for (int j = 0; j < 4; ++j)
            #pragma unroll
            for (int c = 0; c < 16; ++c) lds[EMBA_OFF + (64*j+l)*17 + c] = emb[j][c];
    } else if (w == 1) {
        #pragma unroll
        for (int j = 0; j < 4; ++j)
            #pragma unroll
            for (int c = 0; c < 16; ++c) lds[EMBB_OFF + (64*j+l)*17 + c] = emb[j][c];
    }
    __syncthreads();
    if (w == 2) {
        #pragma unroll
        for (int j = 0; j < 4; ++j)
            #pragma unroll
            for (int c = 0; c < 16; ++c) lds[EMBA_OFF + (64*j+l)*17 + c] += emb[j][c];
    } else if (w == 3) {
        #pragma unroll
        for (int j = 0; j < 4; ++j)
            #pragma unroll
            for (int c = 0; c < 16; ++c) lds[EMBB_OFF + (64*j+l)*17 + c] += emb[j][c];
    }
    __syncthreads();

    // ---- output projection: thread t owns row t ----
    float e[16];
    #pragma unroll
    for (int c = 0; c < 16; ++c)
        e[c] = lds[EMBA_OFF + tid*17 + c] + lds[EMBB_OFF + tid*17 + c];

    float pr[16];
    #pragma unroll
    for (int o = 0; o < 16; ++o) pr[o] = 0.f;
    #pragma unroll
    for (int a = 0; a < 2; ++a) {
        #pragma unroll
        for (int m = 0; m < 8; ++m) {
            const float ev = e[a*8 + m];
            #pragma unroll
            for (int o = 0; o < 16; ++o) pr[o] += ev * lds[WO_OFF + m*32 + a*16 + o];
        }
    }
    float4* po = (float4*)(proj_out + (size_t)bn * NL_ * DOUT_ + (size_t)tid * DOUT_);
    po[0] = make_float4(pr[0],  pr[1],  pr[2],  pr[3]);
    po[1] = make_float4(pr[4],  pr[5],  pr[6],  pr[7]);
    po[2] = make_float4(pr[8],  pr[9],  pr[10], pr[11]);
    po[3] = make_float4(pr[12], pr[13], pr[14], pr[15]);
}

extern "C" void kernel_launch(void* const* d_in, const int* in_sizes, int n_in,
                              void* d_out, int out_size, void* d_ws, size_t ws_size,
                              hipStream_t stream) {
    const float* Q  = (const float*)d_in[0];
    const float* K  = (const float*)d_in[1];
    const float* V  = (const float*)d_in[2];
    const float* Wq = (const float*)d_in[3];
    const float* Wk = (const float*)d_in[4];
    const float* Wv = (const float*)d_in[5];
    const float* Wo = (const float*)d_in[6];

    float* proj = (float*)d_out;
    float* attn = (float*)d_out + PROJ_ELEMS;

    mha_relu_kernel<<<NBN, 256, 0, stream>>>(Q, K, V, Wq, Wk, Wv, Wo, proj, attn);
}